// Round 1
// baseline (3145.449 us; speedup 1.0000x reference)
//
#include <hip/hip_runtime.h>
#include <hip/hip_bf16.h>
#include <cstdint>

#define SENT_LEN   256
#define SENT_BATCH 64
#define WORD_LEN   16
#define EMB        128
#define HID        256
#define CEMB       64
#define CHID       128
#define TAGS       50
#define K_IN       (EMB + CHID)   // 256

__device__ __forceinline__ float sigf(float x) {
    return 1.f / (1.f + __expf(-x));
}
__device__ __forceinline__ float tanhf_fast(float x) {
    x = fminf(fmaxf(x, -15.f), 15.f);
    float e = __expf(2.f * x);
    return (e - 1.f) / (e + 1.f);
}
__device__ __forceinline__ float bf_lo(unsigned u) { return __uint_as_float(u << 16); }
__device__ __forceinline__ float bf_hi(unsigned u) { return __uint_as_float(u & 0xffff0000u); }

// ---------------- K1a: pre_c[ch][g] = b_c[g] + sum_k Wih_c[g][k]*char_emb[ch][k]
__global__ void prep_char(const float* __restrict__ Wih_c, const float* __restrict__ char_emb,
                          const float* __restrict__ bih_c, const float* __restrict__ bhh_c,
                          float* __restrict__ pre_c) {
    int ch = blockIdx.x;      // 128
    int g  = threadIdx.x;     // 512
    float acc = bih_c[g] + bhh_c[g];
    const float* w = Wih_c + g * CEMB;
    const float* e = char_emb + ch * CEMB;
#pragma unroll
    for (int k = 0; k < CEMB; k++) acc += w[k] * e[k];
    pre_c[ch * 512 + g] = acc;
}

// ---------------- K1b: wT8[kb][g][j] = bf16(Whh_w[g][kb*8+j]),  kb<32, g<1024, j<8
__global__ void prep_wT(const float* __restrict__ Whh_w, __hip_bfloat16* __restrict__ wT8) {
    int idx = blockIdx.x * 1024 + threadIdx.x;  // 256 x 1024 = 262144 exact
    int kb = idx >> 13;
    int rem = idx & 8191;
    int g = rem >> 3;
    int j = rem & 7;
    wT8[idx] = __float2bfloat16(Whh_w[g * HID + kb * 8 + j]);
}

// ---------------- K2: char LSTM. 256 blocks (chain t), 512 threads (gate g).
// Whh_c row register-resident (128 fp32/thread); h/c/gates in LDS; fp32 throughout.
__global__ __launch_bounds__(512, 2) void char_lstm(
        const int* __restrict__ words, const float* __restrict__ Whh_c,
        const float* __restrict__ pre_c, float* __restrict__ cf) {
    int t = blockIdx.x;
    int g = threadIdx.x;
    __shared__ __align__(16) float h_s[CHID];
    __shared__ float c_s[CHID];
    __shared__ float g_s[512];

    float4 w4[32];
    const float4* wp = reinterpret_cast<const float4*>(Whh_c + g * CHID);
#pragma unroll
    for (int k = 0; k < 32; k++) w4[k] = wp[k];

    if (g < CHID) { h_s[g] = 0.f; c_s[g] = 0.f; }
    __syncthreads();

    const float4* h4 = reinterpret_cast<const float4*>(h_s);
    for (int s = 0; s < SENT_BATCH * WORD_LEN; s++) {
        int cid = words[s * SENT_LEN + t];
        float pre = pre_c[cid * 512 + g];
        float acc = 0.f;
#pragma unroll
        for (int k = 0; k < 32; k++) {
            float4 hv = h4[k];
            acc += w4[k].x * hv.x + w4[k].y * hv.y + w4[k].z * hv.z + w4[k].w * hv.w;
        }
        g_s[g] = acc + pre;
        __syncthreads();
        if (g < CHID) {
            float ig = sigf(g_s[g]);
            float fg = sigf(g_s[g + 128]);
            float gg = tanhf_fast(g_s[g + 256]);
            float og = sigf(g_s[g + 384]);
            float c = fg * c_s[g] + ig * gg;
            c_s[g] = c;
            float h = og * tanhf_fast(c);
            h_s[g] = h;
            if ((s & 15) == 15)
                cf[t * (SENT_BATCH * CHID) + (s >> 4) * CHID + g] = h;
        }
        __syncthreads();
    }
}

// ---------------- K3: xw[tb][g] = bf16( b_w[g] + sum_k x[tb][k]*Wih_w[g][k] )
// x[tb][k] = k<128 ? word_emb[sent[tb]][k] : cf[tb][k-128].  Tiled fp32 GEMM.
#define BM 64
#define BN 128
#define BK 32
__global__ __launch_bounds__(256) void xw_gemm(
        const int* __restrict__ sentences, const float* __restrict__ word_emb,
        const float* __restrict__ cf, const float* __restrict__ Wih_w,
        const float* __restrict__ bih_w, const float* __restrict__ bhh_w,
        __hip_bfloat16* __restrict__ xw) {
    __shared__ float A_s[BM][BK + 1];
    __shared__ float B_s[BK][BN + 4];
    __shared__ int sid_s[BM];
    int tid = threadIdx.x;
    int row0 = blockIdx.y * BM;
    int col0 = blockIdx.x * BN;
    if (tid < BM) sid_s[tid] = sentences[row0 + tid];
    __syncthreads();

    float acc[8][4] = {};
    int tx = tid & 31, tyy = tid >> 5;

    for (int k0 = 0; k0 < K_IN; k0 += BK) {
#pragma unroll
        for (int i = 0; i < 2; i++) {  // A tile: 64x32 = 512 float4
            int idx = tid + i * 256;
            int r = idx >> 3, k4 = idx & 7;
            int k = k0 + k4 * 4;
            float4 v;
            if (k < EMB)
                v = reinterpret_cast<const float4*>(word_emb + (size_t)sid_s[r] * EMB + k)[0];
            else
                v = reinterpret_cast<const float4*>(cf + (size_t)(row0 + r) * CHID + (k - EMB))[0];
            A_s[r][k4 * 4 + 0] = v.x; A_s[r][k4 * 4 + 1] = v.y;
            A_s[r][k4 * 4 + 2] = v.z; A_s[r][k4 * 4 + 3] = v.w;
        }
#pragma unroll
        for (int i = 0; i < 4; i++) {  // B tile: 128x32 = 1024 float4
            int idx = tid + i * 256;
            int gg = idx >> 3, k4 = idx & 7;
            float4 v = reinterpret_cast<const float4*>(Wih_w + (size_t)(col0 + gg) * K_IN + k0 + k4 * 4)[0];
            B_s[k4 * 4 + 0][gg] = v.x; B_s[k4 * 4 + 1][gg] = v.y;
            B_s[k4 * 4 + 2][gg] = v.z; B_s[k4 * 4 + 3][gg] = v.w;
        }
        __syncthreads();
#pragma unroll
        for (int kk = 0; kk < BK; kk++) {
            float4 bv = reinterpret_cast<const float4*>(&B_s[kk][tx * 4])[0];
#pragma unroll
            for (int i = 0; i < 8; i++) {
                float av = A_s[tyy * 8 + i][kk];
                acc[i][0] += av * bv.x; acc[i][1] += av * bv.y;
                acc[i][2] += av * bv.z; acc[i][3] += av * bv.w;
            }
        }
        __syncthreads();
    }
#pragma unroll
    for (int i = 0; i < 8; i++) {
        int r = row0 + tyy * 8 + i;
#pragma unroll
        for (int j = 0; j < 4; j++) {
            int cg = col0 + tx * 4 + j;
            xw[(size_t)r * 1024 + cg] = __float2bfloat16(acc[i][j] + bih_w[cg] + bhh_w[cg]);
        }
    }
}

// ---------------- K4: word LSTM. 64 blocks (chain b), 1024 threads (gate g).
// Recurrent weights streamed from L2 as packed bf16 (k-major, coalesced 16B/lane).
__global__ __launch_bounds__(1024, 4) void word_lstm(
        const __hip_bfloat16* __restrict__ xw, const uint4* __restrict__ wT8,
        float* __restrict__ h_out) {
    int b = blockIdx.x;
    int g = threadIdx.x;
    __shared__ __align__(16) float h_s[HID];
    __shared__ float c_s[HID];
    __shared__ float g_s[1024];
    if (g < HID) { h_s[g] = 0.f; c_s[g] = 0.f; }
    __syncthreads();
    const float4* h4 = reinterpret_cast<const float4*>(h_s);

    for (int t = 0; t < SENT_LEN; t++) {
        float acc = __bfloat162float(xw[((size_t)t * SENT_BATCH + b) * 1024 + g]);
#pragma unroll 8
        for (int kb = 0; kb < 32; kb++) {
            uint4 wv = wT8[kb * 1024 + g];
            float4 h0 = h4[kb * 2], h1 = h4[kb * 2 + 1];
            acc += bf_lo(wv.x) * h0.x + bf_hi(wv.x) * h0.y
                 + bf_lo(wv.y) * h0.z + bf_hi(wv.y) * h0.w
                 + bf_lo(wv.z) * h1.x + bf_hi(wv.z) * h1.y
                 + bf_lo(wv.w) * h1.z + bf_hi(wv.w) * h1.w;
        }
        g_s[g] = acc;
        __syncthreads();
        if (g < HID) {
            float ig = sigf(g_s[g]);
            float fg = sigf(g_s[g + 256]);
            float gg = tanhf_fast(g_s[g + 512]);
            float og = sigf(g_s[g + 768]);
            float c = fg * c_s[g] + ig * gg;
            c_s[g] = c;
            float h = og * tanhf_fast(c);
            h_s[g] = h;
            h_out[((size_t)t * SENT_BATCH + b) * HID + g] = h;
        }
        __syncthreads();
    }
}

// ---------------- K5: tag projection + log_softmax. 4096 blocks x 256 (4 rows/block, 1 wave/row).
__global__ __launch_bounds__(256) void tag_logsoftmax(
        const float* __restrict__ h_out, const float* __restrict__ W_tag,
        const float* __restrict__ b_tag, float* __restrict__ out) {
    __shared__ float wt_s[TAGS * 257];
    __shared__ float hr_s[4 * HID];
    int tid = threadIdx.x;
    int row0 = blockIdx.x * 4;
#pragma unroll 2
    for (int i = 0; i < TAGS; i++) wt_s[i * 257 + tid] = W_tag[i * HID + tid];
#pragma unroll
    for (int w = 0; w < 4; w++) hr_s[w * HID + tid] = h_out[(size_t)(row0 + w) * HID + tid];
    __syncthreads();

    int w = tid >> 6, l = tid & 63;
    float acc = 0.f;
    if (l < TAGS) {
        acc = b_tag[l];
        const float* hr = hr_s + w * HID;
        const float* wr = wt_s + l * 257;
#pragma unroll 4
        for (int k = 0; k < HID; k++) acc += hr[k] * wr[k];
    }
    float m = (l < TAGS) ? acc : -1e30f;
#pragma unroll
    for (int off = 32; off; off >>= 1) m = fmaxf(m, __shfl_xor(m, off, 64));
    float e = (l < TAGS) ? __expf(acc - m) : 0.f;
    float ssum = e;
#pragma unroll
    for (int off = 32; off; off >>= 1) ssum += __shfl_xor(ssum, off, 64);
    float lse = m + __logf(ssum);
    if (l < TAGS) out[(size_t)(row0 + w) * TAGS + l] = acc - lse;
}

extern "C" void kernel_launch(void* const* d_in, const int* in_sizes, int n_in,
                              void* d_out, int out_size, void* d_ws, size_t ws_size,
                              hipStream_t stream) {
    (void)in_sizes; (void)n_in; (void)out_size; (void)ws_size;
    const int*   sentences = (const int*)d_in[0];
    const int*   words     = (const int*)d_in[1];
    const float* word_emb  = (const float*)d_in[4];
    const float* char_emb  = (const float*)d_in[5];
    const float* Wih_c     = (const float*)d_in[6];
    const float* Whh_c     = (const float*)d_in[7];
    const float* bih_c     = (const float*)d_in[8];
    const float* bhh_c     = (const float*)d_in[9];
    const float* Wih_w     = (const float*)d_in[10];
    const float* Whh_w     = (const float*)d_in[11];
    const float* bih_w     = (const float*)d_in[12];
    const float* bhh_w     = (const float*)d_in[13];
    const float* W_tag     = (const float*)d_in[14];
    const float* b_tag     = (const float*)d_in[15];
    float* out = (float*)d_out;

    char* ws = (char*)d_ws;
    size_t off = 0;
    float* pre_c = (float*)(ws + off);              off += 512 * 128 * sizeof(float);        // 256 KB
    __hip_bfloat16* wT8 = (__hip_bfloat16*)(ws + off); off += 1024 * 256 * sizeof(__hip_bfloat16); // 512 KB
    float* cf = (float*)(ws + off);                 off += (size_t)SENT_LEN * SENT_BATCH * CHID * sizeof(float); // 8.4 MB
    __hip_bfloat16* xw = (__hip_bfloat16*)(ws + off); off += (size_t)SENT_LEN * SENT_BATCH * 1024 * sizeof(__hip_bfloat16); // 33.5 MB
    float* h_out = (float*)(ws + off);              off += (size_t)SENT_LEN * SENT_BATCH * HID * sizeof(float); // 16.8 MB

    hipLaunchKernelGGL(prep_char, dim3(128), dim3(512), 0, stream,
                       Wih_c, char_emb, bih_c, bhh_c, pre_c);
    hipLaunchKernelGGL(prep_wT, dim3(256), dim3(1024), 0, stream, Whh_w, wT8);
    hipLaunchKernelGGL(char_lstm, dim3(256), dim3(512), 0, stream,
                       words, Whh_c, pre_c, cf);
    hipLaunchKernelGGL(xw_gemm, dim3(1024 / BN, (SENT_LEN * SENT_BATCH) / BM), dim3(256), 0, stream,
                       sentences, word_emb, cf, Wih_w, bih_w, bhh_w, xw);
    hipLaunchKernelGGL(word_lstm, dim3(SENT_BATCH), dim3(1024), 0, stream,
                       xw, (const uint4*)wT8, h_out);
    hipLaunchKernelGGL(tag_logsoftmax, dim3((SENT_LEN * SENT_BATCH) / 4), dim3(256), 0, stream,
                       h_out, W_tag, b_tag, out);
}